// Round 1
// baseline (926.939 us; speedup 1.0000x reference)
//
#include <hip/hip_runtime.h>

// ---------------------------------------------------------------------------
// GCN 2-layer inference on MI355X.
// Feature dims hard-coded from reference: F0=512, F1=16, F2=7 (padded to 8).
// ---------------------------------------------------------------------------

#define F0 512
#define F1 16
#define F2 7
#define PW 516   // LDS pitch for transposed W1 (516%4==0 for float4, 2-way bank alias = free)

static __device__ __forceinline__ void atomAddF(float* p, float v) {
    unsafeAtomicAdd(p, v);  // guarantees global_atomic_add_f32 (no CAS loop)
}

// Detect whether edge_index is int64 (odd int32 slots are high words == 0) or int32.
__global__ void k_detect(const int* __restrict__ ei32, int twoE, int* __restrict__ flag) {
    int t = threadIdx.x;                  // one wave
    int idx = 1 + 2 * t;
    int v = (idx < twoE) ? ei32[idx] : 0;
    unsigned long long b = __ballot(v != 0);
    if (t == 0) *flag = (b == 0ULL) ? 1 : 0;   // 1 => int64
}

__global__ void k_deg_init(float* __restrict__ deg, int n) {
    int i = blockIdx.x * blockDim.x + threadIdx.x;
    if (i < n) deg[i] = 1.0f;             // self-loop weight
}

__global__ void k_deg(const int* __restrict__ ei32, const long long* __restrict__ ei64,
                      const int* __restrict__ flag, const float* __restrict__ w,
                      float* __restrict__ deg, int E) {
    int e = blockIdx.x * blockDim.x + threadIdx.x;
    if (e >= E) return;
    int dst = (*flag) ? (int)ei64[(size_t)E + e] : ei32[(size_t)E + e];
    atomAddF(&deg[dst], w[e]);
}

__global__ void k_dinv(float* __restrict__ deg, int n) {
    int i = blockIdx.x * blockDim.x + threadIdx.x;
    if (i < n) {
        float d = deg[i];
        deg[i] = (d > 0.f) ? rsqrtf(d) : 0.f;   // becomes dinv in-place
    }
}

// h1 = x @ W1 ; acc1 = dinv^2 * h1 + b1   (self-loop + bias pre-added)
// 256 threads = 16 rows/block, thread (r=t>>4, j=t&15) computes h1[row][j].
__global__ __launch_bounds__(256) void k_gemm1(
        const float* __restrict__ x, const float* __restrict__ W1,
        const float* __restrict__ b1, const float* __restrict__ dinv,
        float* __restrict__ h1, float* __restrict__ acc1, int n) {
    __shared__ float Wt[F1 * PW];         // W1 transposed: Wt[j][k] = W1[k*16+j]
    int t = threadIdx.x;
    for (int idx = t; idx < F0 * F1; idx += 256) {
        int k = idx >> 4, j = idx & 15;
        Wt[j * PW + k] = W1[idx];
    }
    __syncthreads();
    int r = t >> 4, j = t & 15;
    int row = blockIdx.x * 16 + r;
    if (row >= n) return;
    const float4* xr = (const float4*)(x + (size_t)row * F0);
    const float4* wr = (const float4*)(Wt + j * PW);
    float acc = 0.f;
#pragma unroll 8
    for (int k4 = 0; k4 < F0 / 4; ++k4) {
        float4 xv = xr[k4];
        float4 wv = wr[k4];
        acc += xv.x * wv.x + xv.y * wv.y + xv.z * wv.z + xv.w * wv.w;
    }
    h1[(size_t)row * F1 + j] = acc;
    float di = dinv[row];
    acc1[(size_t)row * F1 + j] = di * di * acc + b1[j];
}

// Edge scatter for layer 1: acc1[dst][j] += norm_e * h1[src][j]; also stores norm.
// tid = e*16 + j  => wave covers 4 edges, atomics hit 4 cache lines.
__global__ __launch_bounds__(256) void k_scatter1(
        const int* __restrict__ ei32, const long long* __restrict__ ei64,
        const int* __restrict__ flag, const float* __restrict__ w,
        const float* __restrict__ dinv, const float* __restrict__ h1,
        float* __restrict__ acc1, float* __restrict__ normb, int E) {
    int t = blockIdx.x * blockDim.x + threadIdx.x;
    int e = t >> 4, j = t & 15;
    if (e >= E) return;
    int src, dst;
    if (*flag) { src = (int)ei64[e]; dst = (int)ei64[(size_t)E + e]; }
    else       { src = ei32[e];      dst = ei32[(size_t)E + e]; }
    float nm = dinv[src] * w[e] * dinv[dst];
    if (j == 0) normb[e] = nm;
    float v = nm * h1[(size_t)src * F1 + j];
    atomAddF(&acc1[(size_t)dst * F1 + j], v);
}

// h2 = relu(acc1) @ W2 ; acc2 = dinv^2 * h2 + b2. One thread per row.
__global__ __launch_bounds__(256) void k_layer2(
        const float* __restrict__ acc1, const float* __restrict__ dinv,
        const float* __restrict__ W2, const float* __restrict__ b2,
        float* __restrict__ h2, float* __restrict__ acc2, int n) {
    __shared__ float sW[F1 * F2];
    __shared__ float sb[F2];
    int t = threadIdx.x;
    if (t < F1 * F2) sW[t] = W2[t];
    if (t < F2) sb[t] = b2[t];
    __syncthreads();
    int i = blockIdx.x * 256 + t;
    if (i >= n) return;
    const float4* a4 = (const float4*)(acc1 + (size_t)i * F1);
    float4 v0 = a4[0], v1 = a4[1], v2 = a4[2], v3 = a4[3];
    float g[F1] = {v0.x, v0.y, v0.z, v0.w, v1.x, v1.y, v1.z, v1.w,
                   v2.x, v2.y, v2.z, v2.w, v3.x, v3.y, v3.z, v3.w};
#pragma unroll
    for (int jj = 0; jj < F1; ++jj) g[jj] = fmaxf(g[jj], 0.f);
    float h[F2];
#pragma unroll
    for (int c = 0; c < F2; ++c) {
        float s = 0.f;
#pragma unroll
        for (int jj = 0; jj < F1; ++jj) s += g[jj] * sW[jj * F2 + c];
        h[c] = s;
    }
    float di = dinv[i], s2 = di * di;
    float4 o0 = make_float4(h[0], h[1], h[2], h[3]);
    float4 o1 = make_float4(h[4], h[5], h[6], 0.f);
    ((float4*)(h2 + (size_t)i * 8))[0] = o0;
    ((float4*)(h2 + (size_t)i * 8))[1] = o1;
    float4 p0 = make_float4(s2 * h[0] + sb[0], s2 * h[1] + sb[1],
                            s2 * h[2] + sb[2], s2 * h[3] + sb[3]);
    float4 p1 = make_float4(s2 * h[4] + sb[4], s2 * h[5] + sb[5],
                            s2 * h[6] + sb[6], 0.f);
    ((float4*)(acc2 + (size_t)i * 8))[0] = p0;
    ((float4*)(acc2 + (size_t)i * 8))[1] = p1;
}

// Edge scatter for layer 2: acc2[dst][c] += norm_e * h2[src][c]. tid = e*8 + c.
__global__ __launch_bounds__(256) void k_scatter2(
        const int* __restrict__ ei32, const long long* __restrict__ ei64,
        const int* __restrict__ flag, const float* __restrict__ normb,
        const float* __restrict__ h2, float* __restrict__ acc2, int E) {
    int t = blockIdx.x * blockDim.x + threadIdx.x;
    int e = t >> 3, c = t & 7;
    if (e >= E || c >= F2) return;
    int src, dst;
    if (*flag) { src = (int)ei64[e]; dst = (int)ei64[(size_t)E + e]; }
    else       { src = ei32[e];      dst = ei32[(size_t)E + e]; }
    float nm = normb[e];
    float v = nm * h2[(size_t)src * 8 + c];
    atomAddF(&acc2[(size_t)dst * 8 + c], v);
}

__global__ __launch_bounds__(256) void k_logsoftmax(
        const float* __restrict__ acc2, float* __restrict__ out, int n) {
    int i = blockIdx.x * 256 + threadIdx.x;
    if (i >= n) return;
    const float4* a4 = (const float4*)(acc2 + (size_t)i * 8);
    float4 a = a4[0], b = a4[1];
    float v[F2] = {a.x, a.y, a.z, a.w, b.x, b.y, b.z};
    float m = v[0];
#pragma unroll
    for (int c = 1; c < F2; ++c) m = fmaxf(m, v[c]);
    float s = 0.f;
#pragma unroll
    for (int c = 0; c < F2; ++c) s += __expf(v[c] - m);
    float ls = __logf(s) + m;
#pragma unroll
    for (int c = 0; c < F2; ++c) out[(size_t)i * F2 + c] = v[c] - ls;
}

extern "C" void kernel_launch(void* const* d_in, const int* in_sizes, int n_in,
                              void* d_out, int out_size, void* d_ws, size_t ws_size,
                              hipStream_t stream) {
    const float* x  = (const float*)d_in[0];
    const int* ei32 = (const int*)d_in[1];
    const long long* ei64 = (const long long*)d_in[1];
    const float* w  = (const float*)d_in[2];
    const float* W1 = (const float*)d_in[3];
    const float* b1 = (const float*)d_in[4];
    const float* W2 = (const float*)d_in[5];
    const float* b2 = (const float*)d_in[6];
    float* out = (float*)d_out;

    const int n = in_sizes[0] / F0;       // 100000
    const int E = in_sizes[2];            // 3200000

    // workspace layout (floats)
    float* ws   = (float*)d_ws;
    float* deg  = ws;                     // n   (becomes dinv in-place)
    float* h1   = deg  + n;               // n*16
    float* acc1 = h1   + (size_t)n * F1;  // n*16
    float* h2   = acc1 + (size_t)n * F1;  // n*8
    float* acc2 = h2   + (size_t)n * 8;   // n*8
    float* nb   = acc2 + (size_t)n * 8;   // E
    int* flag   = (int*)(nb + E);         // 1

    const int B = 256;
    k_detect<<<1, 64, 0, stream>>>(ei32, 2 * E, flag);
    k_deg_init<<<(n + B - 1) / B, B, 0, stream>>>(deg, n);
    k_deg<<<(E + B - 1) / B, B, 0, stream>>>(ei32, ei64, flag, w, deg, E);
    k_dinv<<<(n + B - 1) / B, B, 0, stream>>>(deg, n);
    k_gemm1<<<(n + 15) / 16, B, 0, stream>>>(x, W1, b1, deg, h1, acc1, n);
    {
        long long tot = (long long)E * F1;
        k_scatter1<<<(int)((tot + B - 1) / B), B, 0, stream>>>(
            ei32, ei64, flag, w, deg, h1, acc1, nb, E);
    }
    k_layer2<<<(n + B - 1) / B, B, 0, stream>>>(acc1, deg, W2, b2, h2, acc2, n);
    {
        long long tot = (long long)E * 8;
        k_scatter2<<<(int)((tot + B - 1) / B), B, 0, stream>>>(
            ei32, ei64, flag, nb, h2, acc2, E);
    }
    k_logsoftmax<<<(n + B - 1) / B, B, 0, stream>>>(acc2, out, n);
}